// Round 8
// baseline (1877.350 us; speedup 1.0000x reference)
//
#include <hip/hip_runtime.h>
#include <stdint.h>

// GraphSAGE fused layer, MI355X (gfx950). All tensors fp32.
// R8 = measurement round. Production path = R5 kernel verbatim (best: NT loads
// + 4-KB stagger, ~4.0 TB/s scan). Added: a pure-read probe that streams adj
// 4x (4.295 GB) with zero processing so it lands in the top-5 profile rows
// with its own counters -> direct measurement of the achievable pure-read BW
// on this allocation. Decides roofline vs. scan-restructure for R9.

#define NROWS   16384
#define DDIM    64
#define MAXNNZ  256
#define NBLOCKS 4096
#define PROBE_BLOCKS 8192
#define CHUNKS  ((size_t)NROWS * NROWS / 4)   // 2^26 16-B chunks

typedef uint32_t u32x4 __attribute__((ext_vector_type(4)));

// ---------------- pure-read probe: 4 passes over adj, XOR sink ----------------
__global__ __launch_bounds__(256) void read_probe(const float* __restrict__ adj,
                                                  uint32_t* __restrict__ sink) {
    const size_t T   = (size_t)PROBE_BLOCKS * 256;        // 2,097,152 threads
    const size_t tid = (size_t)blockIdx.x * 256 + threadIdx.x;
    const u32x4* p   = reinterpret_cast<const u32x4*>(adj);
    const size_t MASK = CHUNKS - 1;                        // CHUNKS is 2^26
    uint32_t acc = 0;
#pragma unroll 1
    for (size_t base = tid; base < 4 * CHUNKS; base += 4 * T) {  // 32 iters
        const u32x4 c0 = p[(base)         & MASK];
        const u32x4 c1 = p[(base + T)     & MASK];
        const u32x4 c2 = p[(base + 2 * T) & MASK];
        const u32x4 c3 = p[(base + 3 * T) & MASK];
        acc ^= (c0.x | c0.y | c0.z | c0.w) ^ (c1.x | c1.y | c1.z | c1.w)
             ^ (c2.x | c2.y | c2.z | c2.w) ^ (c3.x | c3.y | c3.z | c3.w);
    }
#pragma unroll
    for (int off = 32; off >= 1; off >>= 1) acc ^= (uint32_t)__shfl_xor((int)acc, off);
    if ((threadIdx.x & 63) == 0)
        sink[blockIdx.x * 4 + (threadIdx.x >> 6)] = acc;
}

// ---------------- production: R5 fused kernel (verbatim) ----------------
__global__ __launch_bounds__(256, 4) void sage_fused(
    const float* __restrict__ X,     // (N, 64)
    const float* __restrict__ adj,   // (N, N)
    const float* __restrict__ W,     // (128, 64) row-major, cache-hot
    const float* __restrict__ bias,  // (64,)
    float* __restrict__ out)         // (N, 64)
{
    __shared__ int   slist[4][MAXNNZ];
    __shared__ int   scnt[4];
    __shared__ float scat[4][2 * DDIM];

    const int tid  = threadIdx.x;
    const int lane = tid & 63;
    const int w    = tid >> 6;
    const int row  = blockIdx.x * 4 + w;

    const float bv = bias[lane];

    if (lane == 0) scnt[w] = 0;
    __builtin_amdgcn_wave_barrier();

    const int start = (row * 7 + (row >> 4)) & 15;
    const u32x4* rowp = reinterpret_cast<const u32x4*>(adj + (size_t)row * NROWS);

    u32x4 buf[2][4];
    {
        const int ss0 = start;
        const int ss1 = (start + 1) & 15;
#pragma unroll
        for (int q = 0; q < 4; ++q)
            buf[0][q] = __builtin_nontemporal_load(&rowp[ss0 * 256 + q * 64 + lane]);
#pragma unroll
        for (int q = 0; q < 4; ++q)
            buf[1][q] = __builtin_nontemporal_load(&rowp[ss1 * 256 + q * 64 + lane]);
    }

#pragma unroll 2
    for (int s = 0; s < 16; ++s) {
        const int cur = s & 1;
        const int ss  = (s + start) & 15;
#pragma unroll
        for (int q = 0; q < 4; ++q) {
            const u32x4 vv = buf[cur][q];
            if (vv.x | vv.y | vv.z | vv.w) {
                const int base = (ss * 256 + q * 64 + lane) * 4;
                const uint32_t w4[4] = { vv.x, vv.y, vv.z, vv.w };
#pragma unroll
                for (int j = 0; j < 4; ++j) {
                    if (w4[j]) {
                        const int p = atomicAdd(&scnt[w], 1);
                        if (p < MAXNNZ) slist[w][p] = base + j;
                    }
                }
            }
        }
        if (s < 14) {
            const int ssn = (s + 2 + start) & 15;
#pragma unroll
            for (int q = 0; q < 4; ++q)
                buf[cur][q] = __builtin_nontemporal_load(&rowp[ssn * 256 + q * 64 + lane]);
        }
    }
    __builtin_amdgcn_wave_barrier();

    const int nnz = scnt[w];
    const int cn  = (nnz < MAXNNZ) ? nnz : MAXNNZ;

    float acc = 0.0f;
    int k = 0;
    for (; k + 4 <= cn; k += 4) {
        const int j0 = slist[w][k], j1 = slist[w][k + 1];
        const int j2 = slist[w][k + 2], j3 = slist[w][k + 3];
        const float a0 = X[(size_t)j0 * DDIM + lane];
        const float a1 = X[(size_t)j1 * DDIM + lane];
        const float a2 = X[(size_t)j2 * DDIM + lane];
        const float a3 = X[(size_t)j3 * DDIM + lane];
        acc += (a0 + a1) + (a2 + a3);
    }
    for (; k < cn; ++k) acc += X[(size_t)slist[w][k] * DDIM + lane];

    const float xi = X[(size_t)row * DDIM + lane];
    const float h  = (acc + xi) / ((float)nnz + 1.0f);
    scat[w][lane]        = xi;
    scat[w][DDIM + lane] = h;
    __builtin_amdgcn_wave_barrier();

    float z0 = bv, z1 = 0.0f, z2 = 0.0f, z3 = 0.0f;
#pragma unroll 8
    for (int kk = 0; kk < 2 * DDIM; kk += 4) {
        z0 = fmaf(scat[w][kk + 0], W[(kk + 0) * DDIM + lane], z0);
        z1 = fmaf(scat[w][kk + 1], W[(kk + 1) * DDIM + lane], z1);
        z2 = fmaf(scat[w][kk + 2], W[(kk + 2) * DDIM + lane], z2);
        z3 = fmaf(scat[w][kk + 3], W[(kk + 3) * DDIM + lane], z3);
    }
    float z = (z0 + z1) + (z2 + z3);
    z = fmaxf(z, 0.0f);

    float s2 = z * z;
#pragma unroll
    for (int off = 32; off >= 1; off >>= 1) s2 += __shfl_xor(s2, off);
    const float inv = 1.0f / fmaxf(sqrtf(s2), 1e-12f);
    out[(size_t)row * DDIM + lane] = z * inv;
}

extern "C" void kernel_launch(void* const* d_in, const int* in_sizes, int n_in,
                              void* d_out, int out_size, void* d_ws, size_t ws_size,
                              hipStream_t stream) {
    const float* X   = (const float*)d_in[0];
    const float* adj = (const float*)d_in[1];
    const float* W   = (const float*)d_in[2];
    const float* b   = (const float*)d_in[3];
    float* out = (float*)d_out;

    sage_fused<<<NBLOCKS, 256, 0, stream>>>(X, adj, W, b, out);
    read_probe<<<PROBE_BLOCKS, 256, 0, stream>>>(adj, (uint32_t*)d_ws);
}

// Round 9
// 1341.761 us; speedup vs baseline: 1.3992x; 1.3992x over previous
//
#include <hip/hip_runtime.h>
#include <stdint.h>

// GraphSAGE fused layer, MI355X (gfx950). All tensors fp32.
// N=16384, D=64, adj = binary fp32 mask (1.074 GB), avg deg ~32.
// R8 probe: plain flat reads of adj sustain >6.4 TB/s (probe ~7.3 TB/s), so
// the ~4 TB/s scan plateau was PROCESSING-coupled stalls: divergent branch +
// LDS atomicAdd whose returned position the wave must wait for, draining the
// load pipeline. R9 scan is probe-shaped: ballot-compaction (no atomics, no
// result-dependent waits), packed (chunk,mask) entries, fire-and-forget
// ds_write. One wave per row, depth-8 pipeline, no __syncthreads.

#define NROWS    16384
#define DDIM     64
#define MAXCHUNK 256      // nonzero 16-B chunks per row: <= nnz (mean 32, sigma 5.7)
#define NBLOCKS  4096
#define PIPE     8        // outstanding 16-B loads per lane

typedef uint32_t u32x4 __attribute__((ext_vector_type(4)));

__global__ __launch_bounds__(256, 6) void sage_fused(
    const float* __restrict__ X,     // (N, 64)
    const float* __restrict__ adj,   // (N, N)
    const float* __restrict__ W,     // (128, 64) row-major, cache-hot
    const float* __restrict__ bias,  // (64,)
    float* __restrict__ out)         // (N, 64)
{
    __shared__ int   slist[4][MAXCHUNK];  // packed (chunkIdx<<4)|mask4 entries
    __shared__ float scat[4][2 * DDIM];   // per-wave [x_i | h_neigh]

    const int tid  = threadIdx.x;
    const int lane = tid & 63;
    const int w    = tid >> 6;
    const int row  = blockIdx.x * 4 + w;      // one wave per row

    const float bv = bias[lane];

    // ---- Scan the 64 KB adj row: 64 groups of 1 KB (u32x4/lane), 4-KB stagger.
    const int start = ((row * 7 + (row >> 4)) & 15) * 4;   // group units
    const u32x4* rowp = reinterpret_cast<const u32x4*>(adj + (size_t)row * NROWS);

    u32x4 buf[PIPE];
#pragma unroll
    for (int i = 0; i < PIPE; ++i)
        buf[i] = rowp[((start + i) & 63) * 64 + lane];

    int cnt = 0;   // wave-uniform running count of nonzero chunks
#pragma unroll 1
    for (int so = 0; so < 64; so += PIPE) {
#pragma unroll
        for (int i = 0; i < PIPE; ++i) {
            const int g = (start + so + i) & 63;          // group being processed
            const u32x4 vv = buf[i];
            const bool nz = (vv.x | vv.y | vv.z | vv.w) != 0;  // fp32 0.0f == 0 bits
            const uint64_t bal = __ballot(nz);
            if (bal) {                                    // wave-uniform branch
                // adj values are exactly 0.0f or 1.0f (0x3F800000: bit29 set).
                const uint32_t m = ((vv.x >> 29) & 1u) | ((vv.y >> 28) & 2u)
                                 | ((vv.z >> 27) & 4u) | ((vv.w >> 26) & 8u);
                const int prefix = __builtin_amdgcn_mbcnt_hi(
                    (uint32_t)(bal >> 32),
                    __builtin_amdgcn_mbcnt_lo((uint32_t)bal, 0));
                if (nz) {                                 // exec-masked ds_write, no wait
                    const int pos = cnt + prefix;
                    if (pos < MAXCHUNK)
                        slist[w][pos] = (((g << 6) + lane) << 4) | (int)m;
                }
                cnt += (int)__popcll(bal);                // scalar s_bcnt1
            }
            if (so + PIPE < 64)                           // refill with group +PIPE
                buf[i] = rowp[((start + so + i + PIPE) & 63) * 64 + lane];
        }
    }
    __builtin_amdgcn_wave_barrier();   // order ds_write -> ds_read (same wave)

    const int cn = (cnt < MAXCHUNK) ? cnt : MAXCHUNK;

    // ---- Gather-accumulate neighbor X rows; decode packed entries.
    // Entry masks are wave-uniform -> branches are s_cbranch (no divergence).
    float acc = 0.0f;
    int nnz = 0;                        // element-level nonzero count (= rowsum)
    for (int k = 0; k < cn; ++k) {
        const int e  = slist[w][k];     // LDS broadcast
        const int ci = e >> 4;          // chunk index within row (0..4095)
        const uint32_t m = e & 15u;
        nnz += __popc(m);
        const float* xb = X + (size_t)ci * 4 * DDIM + lane;
        if (m & 1u) acc += xb[0 * DDIM];
        if (m & 2u) acc += xb[1 * DDIM];
        if (m & 4u) acc += xb[2 * DDIM];
        if (m & 8u) acc += xb[3 * DDIM];
    }

    const float xi = X[(size_t)row * DDIM + lane];
    const float h  = (acc + xi) / ((float)nnz + 1.0f);   // deg = rowsum+1 >= 1
    scat[w][lane]        = xi;
    scat[w][DDIM + lane] = h;
    __builtin_amdgcn_wave_barrier();

    // ---- GEMV: z[d] = b[d] + sum_k cat[k] * W[k][d]; W is L1/L2-hot.
    float z0 = bv, z1 = 0.0f, z2 = 0.0f, z3 = 0.0f;
#pragma unroll 8
    for (int kk = 0; kk < 2 * DDIM; kk += 4) {
        z0 = fmaf(scat[w][kk + 0], W[(kk + 0) * DDIM + lane], z0);
        z1 = fmaf(scat[w][kk + 1], W[(kk + 1) * DDIM + lane], z1);
        z2 = fmaf(scat[w][kk + 2], W[(kk + 2) * DDIM + lane], z2);
        z3 = fmaf(scat[w][kk + 3], W[(kk + 3) * DDIM + lane], z3);
    }
    float z = (z0 + z1) + (z2 + z3);
    z = fmaxf(z, 0.0f);

    // ---- Row L2-norm over the 64 lanes, normalize, store.
    float s2 = z * z;
#pragma unroll
    for (int off = 32; off >= 1; off >>= 1) s2 += __shfl_xor(s2, off);
    const float inv = 1.0f / fmaxf(sqrtf(s2), 1e-12f);
    out[(size_t)row * DDIM + lane] = z * inv;
}

extern "C" void kernel_launch(void* const* d_in, const int* in_sizes, int n_in,
                              void* d_out, int out_size, void* d_ws, size_t ws_size,
                              hipStream_t stream) {
    const float* X   = (const float*)d_in[0];
    const float* adj = (const float*)d_in[1];
    const float* W   = (const float*)d_in[2];
    const float* b   = (const float*)d_in[3];
    float* out = (float*)d_out;
    sage_fused<<<NBLOCKS, 256, 0, stream>>>(X, adj, W, b, out);
}